// Round 6
// baseline (288.858 us; speedup 1.0000x reference)
//
#include <hip/hip_runtime.h>

typedef _Float16 half8 __attribute__((ext_vector_type(8)));
typedef _Float16 half4 __attribute__((ext_vector_type(4)));
typedef float f32x4 __attribute__((ext_vector_type(4)));

#define ROWS 64
#define HP 136                  // h row pitch (halfs): 128 + 8 pad; 272 B
#define HBUFSZ (ROWS * HP)
#define LOG2E 1.442695041f
#define MFMA(a,b,c) __builtin_amdgcn_mfma_f32_16x16x32_f16((a),(b),(c),0,0,0)

// r0 structure (234us) + encoder split-half pipeline: each barrier interval
// carries MFMA for one half AND gates (trans) for the other half, so matrix
// and trans pipes get concurrent work (m114: pipes overlap when both fed).
// setprio REMOVED (r5: -8% in lockstep structure, matches m190).
__global__ __launch_bounds__(512, 2)
void traj_gru(const float* __restrict__ history,
              const float* __restrict__ w_ih, const float* __restrict__ w_hh,
              const float* __restrict__ b_ih, const float* __restrict__ b_hh,
              const float* __restrict__ w1, const float* __restrict__ b1,
              const float* __restrict__ w2, const float* __restrict__ b2,
              float* __restrict__ out)
{
    __shared__ __align__(16) _Float16 hbuf[2 * HBUFSZ];     // 34,816 B; a1 aliases dead half
    __shared__ __align__(16) _Float16 xhist[50 * ROWS * 8]; // 51,200 B [t][row][8] (x0..x5,1,0)
    __shared__ __align__(16) _Float16 xdec[ROWS * 8];       //  1,024 B
    __shared__ __align__(16) _Float16 w2f[4 * 4 * 16 * 8];  //  4,096 B => 91,136 total

    const int tid  = threadIdx.x;
    const int wave = tid >> 6;
    const int lane = tid & 63;
    const int ln16 = lane & 15;
    const int q    = lane >> 4;
    const int sw   = ln16 & 3;               // head-phase2 a1s read swizzle
    const int rowbase = blockIdx.x * ROWS;
    const int dbase = wave * 16;             // gru: wave's h-dims; head: wave's a1-dims
    const int bblk  = wave >> 1;             // head a1s write swizzle
    const int colin = ((wave & 1) << 4) | ln16;

    // ---- init LDS: zeros first, barrier, then fills ----
    for (int i = tid; i < 2 * HBUFSZ; i += 512) hbuf[i] = (_Float16)0;
    for (int i = tid; i < ROWS * 8; i += 512) xdec[i] = (_Float16)0;
    for (int i = tid; i < 4 * 4 * 16 * 8; i += 512) w2f[i] = (_Float16)0;
    __syncthreads();
    for (int idx = tid; idx < 50 * ROWS * 8; idx += 512) {  // [t][row][8]: x0..x5, 1.0, 0.0
        int c = idx & 7, tr = idx >> 3;
        int r = tr & (ROWS - 1), t = tr >> 6;
        _Float16 v;
        if (c < 6)       v = (_Float16)history[(rowbase + r) * 300 + t * 6 + c];
        else if (c == 6) v = (_Float16)1.0f;   // bias slot
        else             v = (_Float16)0.0f;
        xhist[idx] = v;
    }
    if (tid < ROWS) xdec[tid * 8 + 6] = (_Float16)1.0f;   // decoder bias slot
    for (int idx = tid; idx < 6 * 128; idx += 512) {      // w2 -> B-frag layout
        int n = idx >> 7, k = idx & 127;
        int kt = k >> 5, qq = (k >> 3) & 3, j = k & 7;
        w2f[((kt * 4 + qq) * 16 + n) * 8 + j] = (_Float16)w2[n * 128 + k];
    }

    // ---- persistent register fragments ----
    half8 Wg[3][4];
    #pragma unroll
    for (int g = 0; g < 3; ++g) {
        float sc = (g < 2) ? -LOG2E : -2.0f * LOG2E;
        #pragma unroll
        for (int kt = 0; kt < 4; ++kt) {
            const float* p = w_hh + (g * 128 + dbase + ln16) * 128 + kt * 32 + q * 8;
            half8 v;
            #pragma unroll
            for (int j = 0; j < 8; ++j) v[j] = (_Float16)(p[j] * sc);
            Wg[g][kt] = v;
        }
    }
    half8 Wx[3];     // A-side x-weights: q==0 rows k<6; bias via acc init
    #pragma unroll
    for (int g = 0; g < 3; ++g) {
        float sc = (g < 2) ? -LOG2E : -2.0f * LOG2E;
        half8 v;
        #pragma unroll
        for (int j = 0; j < 8; ++j) v[j] = (_Float16)0.0f;
        if (q == 0) {
            #pragma unroll
            for (int j = 0; j < 6; ++j) v[j] = (_Float16)(w_ih[(g * 128 + dbase + ln16) * 6 + j] * sc);
        }
        Wx[g] = v;
    }
    f32x4 brr, brz, bin, bhn;
    #pragma unroll
    for (int i = 0; i < 4; ++i) {
        int d = dbase + q * 4 + i;
        brr[i] = (b_ih[d]       + b_hh[d]      ) * (-LOG2E);
        brz[i] = (b_ih[128 + d] + b_hh[128 + d]) * (-LOG2E);
        bin[i] = b_ih[256 + d] * (-2.0f * LOG2E);
        bhn[i] = b_hh[256 + d] * (-2.0f * LOG2E);
    }
    half8 Bw1[4];
    #pragma unroll
    for (int kt = 0; kt < 4; ++kt) {
        const float* p = w1 + (dbase + ln16) * 128 + kt * 32 + q * 8;
        half8 v;
        #pragma unroll
        for (int j = 0; j < 8; ++j) v[j] = (_Float16)p[j];
        Bw1[kt] = v;
    }
    const float b1r = b1[dbase + ln16];
    const float b2r = (ln16 < 6) ? b2[ln16] : 0.0f;

    float hp[4][4] = {};  // h_prev: lane holds (batch=c*16+ln16, dim=dbase+q*4+i)

    __syncthreads();

    // ================= encoder: split-half pipelined =================
    // half A = chunks {0,1}, half B = chunks {2,3}. mfma X(t) reads buf[t&1];
    // gates X(t) writes buf[(t&1)^1]. Each interval: mfma(one half) + gates(other).
    {
        f32x4 aA[2][4], aB[2][4];
        auto emfma = [&](int t, int c, f32x4 (&acc)[4]) {
            const _Float16* rp = hbuf + (t & 1) * HBUFSZ + (c * 16 + ln16) * HP;
            half8 b0 = *(const half8*)(rp +  0 + q * 8);
            half8 b1v = *(const half8*)(rp + 32 + q * 8);
            half8 b2v = *(const half8*)(rp + 64 + q * 8);
            half8 b3 = *(const half8*)(rp + 96 + q * 8);
            half8 bx = *(const half8*)(xhist + ((t * ROWS + c * 16 + ln16) << 3));
            f32x4 r = brr, z = brz, hh = bhn, n = bin;
            r = MFMA(Wg[0][0], b0, r);  z = MFMA(Wg[1][0], b0, z);  hh = MFMA(Wg[2][0], b0, hh);
            r = MFMA(Wg[0][1], b1v, r); z = MFMA(Wg[1][1], b1v, z); hh = MFMA(Wg[2][1], b1v, hh);
            r = MFMA(Wg[0][2], b2v, r); z = MFMA(Wg[1][2], b2v, z); hh = MFMA(Wg[2][2], b2v, hh);
            r = MFMA(Wg[0][3], b3, r);  z = MFMA(Wg[1][3], b3, z);  hh = MFMA(Wg[2][3], b3, hh);
            r = MFMA(Wx[0], bx, r);
            z = MFMA(Wx[1], bx, z);
            n = MFMA(Wx[2], bx, n);
            acc[0] = r; acc[1] = z; acc[2] = hh; acc[3] = n;
        };
        auto egates = [&](int t, int c, f32x4 (&acc)[4]) {
            _Float16* hn = hbuf + ((t & 1) ^ 1) * HBUFSZ;
            half4 hv;
            #pragma unroll
            for (int i = 0; i < 4; ++i) {
                float rr = __builtin_amdgcn_rcpf(1.0f + __builtin_amdgcn_exp2f(acc[0][i]));
                float zz = __builtin_amdgcn_rcpf(1.0f + __builtin_amdgcn_exp2f(acc[1][i]));
                float tt = acc[3][i] + rr * acc[2][i];
                float nn = 2.0f * __builtin_amdgcn_rcpf(1.0f + __builtin_amdgcn_exp2f(tt)) - 1.0f;
                float h = nn + zz * (hp[c][i] - nn);
                hp[c][i] = h;
                hv[i] = (_Float16)h;
            }
            *(half4*)(hn + (c * 16 + ln16) * HP + dbase + q * 4) = hv;
        };

        emfma(0, 0, aA[0]); emfma(0, 1, aA[1]);   // prologue: mfma A(0)
        #pragma unroll 1
        for (int t = 0; t < 50; ++t) {
            // interval: mfma B(t) || gates A(t)
            emfma(t, 2, aB[0]);
            egates(t, 0, aA[0]);
            emfma(t, 3, aB[1]);
            egates(t, 1, aA[1]);
            __syncthreads();
            if (t < 49) {
                // interval: mfma A(t+1) || gates B(t)
                emfma(t + 1, 0, aA[0]);
                egates(t, 2, aB[0]);
                emfma(t + 1, 1, aA[1]);
                egates(t, 3, aB[1]);
                __syncthreads();
            }
        }
        egates(49, 2, aB[0]);   // epilogue: gates B(49) -> buf[0]
        egates(49, 3, aB[1]);
        __syncthreads();
    }
    // h(49) now fully in buf[0]

    // ================= decoder: r0-proven structure =================
    auto gru_step = [&](int p, int t, bool enc) {
        const _Float16* hb = hbuf + p * HBUFSZ;
        _Float16*       hn = hbuf + (p ^ 1) * HBUFSZ;
        half8 Bf[2][4], Bx[2];
        f32x4 ar[2], az[2], ahh[2], an[2];

        auto loadB = [&](int c, int buf) {
            const _Float16* rp = hb + (c * 16 + ln16) * HP;
            #pragma unroll
            for (int kt = 0; kt < 4; ++kt)
                Bf[buf][kt] = *(const half8*)(rp + kt * 32 + q * 8);
            if (enc) {   // single b128: [x0..x5, 1.0, 0.0] pre-packed at init
                Bx[buf] = *(const half8*)(xhist + ((t * ROWS + c * 16 + ln16) << 3));
            } else {
                Bx[buf] = *(const half8*)(xdec + (c * 16 + ln16) * 8);      // broadcast
            }
        };
        auto mfmas = [&](int buf) {
            f32x4 r = brr, z = brz, hh = bhn, n = bin;
            #pragma unroll
            for (int kt = 0; kt < 4; ++kt) {
                r  = MFMA(Wg[0][kt], Bf[buf][kt], r);
                z  = MFMA(Wg[1][kt], Bf[buf][kt], z);
                hh = MFMA(Wg[2][kt], Bf[buf][kt], hh);
            }
            r = MFMA(Wx[0], Bx[buf], r);
            z = MFMA(Wx[1], Bx[buf], z);
            n = MFMA(Wx[2], Bx[buf], n);
            ar[buf] = r; az[buf] = z; ahh[buf] = hh; an[buf] = n;
        };
        auto gates = [&](int c, int cb) {
            half4 hv;
            #pragma unroll
            for (int i = 0; i < 4; ++i) {
                float r = __builtin_amdgcn_rcpf(1.0f + __builtin_amdgcn_exp2f(ar[cb][i]));
                float z = __builtin_amdgcn_rcpf(1.0f + __builtin_amdgcn_exp2f(az[cb][i]));
                float tt = an[cb][i] + r * ahh[cb][i];
                float n = 2.0f * __builtin_amdgcn_rcpf(1.0f + __builtin_amdgcn_exp2f(tt)) - 1.0f;
                float h = n + z * (hp[c][i] - n);
                hp[c][i] = h;
                hv[i] = (_Float16)h;
            }
            *(half4*)(hn + (c * 16 + ln16) * HP + dbase + q * 4) = hv;
        };

        loadB(0, 0); mfmas(0);
        #pragma unroll
        for (int c = 0; c < 4; ++c) {
            const int cb = c & 1;
            if (c < 3) { loadB(c + 1, cb ^ 1); mfmas(cb ^ 1); }
            gates(c, cb);
        }
        __syncthreads();
    };

    auto head_step = [&](int f, int p) {
        const _Float16* hb = hbuf + p * HBUFSZ;
        _Float16*       a1 = hbuf + (p ^ 1) * HBUFSZ;   // dead ping-pong half
        half8 Ah[2][4];
        f32x4 aa[2];
        auto loadA = [&](int c, int buf) {
            const _Float16* rp = hb + (c * 16 + ln16) * HP;
            #pragma unroll
            for (int kt = 0; kt < 4; ++kt)
                Ah[buf][kt] = *(const half8*)(rp + kt * 32 + q * 8);   // plain [batch][dim]
        };
        auto mfh = [&](int buf) {
            f32x4 a = {0,0,0,0};
            #pragma unroll
            for (int kt = 0; kt < 4; ++kt) a = MFMA(Ah[buf][kt], Bw1[kt], a);
            aa[buf] = a;
        };
        auto relu4 = [&](int c, int cb) {
            #pragma unroll
            for (int i = 0; i < 4; ++i) {
                float v = aa[cb][i] + b1r;
                v = v > 0.0f ? v : 0.0f;
                a1[(c * 16 + q * 4 + i) * HP + ((bblk ^ i) << 5) + colin] = (_Float16)v;
            }
        };
        loadA(0, 0); mfh(0);
        #pragma unroll
        for (int c = 0; c < 4; ++c) {
            const int cb = c & 1;
            if (c < 3) { loadA(c + 1, cb ^ 1); mfh(cb ^ 1); }
            relu4(c, cb);
        }
        __syncthreads();
        if (wave < 4) {   // phase 2: A=a1 (m=batch), B=w2f (n=out-dim)
            const _Float16* rp = a1 + (wave * 16 + ln16) * HP;
            f32x4 o = {0,0,0,0};
            #pragma unroll
            for (int kt = 0; kt < 4; ++kt) {
                half8 Aa = *(const half8*)(rp + ((kt ^ sw) << 5) + q * 8);
                half8 Bw = *(const half8*)&w2f[((kt * 4 + q) * 16 + ln16) * 8];
                o = MFMA(Aa, Bw, o);
            }
            if (ln16 < 6) {
                #pragma unroll
                for (int i = 0; i < 4; ++i) {
                    int row = wave * 16 + q * 4 + i;
                    float v = o[i] + b2r;
                    out[(rowbase + row) * 180 + f * 6 + ln16] = v;
                    xdec[row * 8 + ln16] = (_Float16)v;   // next decoder x (slots 0..5)
                }
            }
        }
        __syncthreads();
    };

    int p = 0;
    #pragma unroll 1
    for (int f = 0; f < 30; ++f) {
        gru_step(p, f == 0 ? 49 : 0, f == 0);   // f=0: x = history[:,49]
        p ^= 1;
        head_step(f, p);
    }
}

extern "C" void kernel_launch(void* const* d_in, const int* in_sizes, int n_in,
                              void* d_out, int out_size, void* d_ws, size_t ws_size,
                              hipStream_t stream) {
    (void)in_sizes; (void)n_in; (void)d_ws; (void)ws_size; (void)out_size;
    traj_gru<<<dim3(16384 / ROWS), dim3(512), 0, stream>>>(
        (const float*)d_in[0], (const float*)d_in[1], (const float*)d_in[2],
        (const float*)d_in[3], (const float*)d_in[4], (const float*)d_in[5],
        (const float*)d_in[6], (const float*)d_in[7], (const float*)d_in[8],
        (float*)d_out);
}

// Round 7
// 272.054 us; speedup vs baseline: 1.0618x; 1.0618x over previous
//
#include <hip/hip_runtime.h>

typedef _Float16 half8 __attribute__((ext_vector_type(8)));
typedef _Float16 half4 __attribute__((ext_vector_type(4)));
typedef float f32x4 __attribute__((ext_vector_type(4)));
typedef int int4v __attribute__((ext_vector_type(4)));

#define ROWS 64
#define HP 136                  // h row pitch (halfs): 128 + 8 pad; 272 B
#define HBUFSZ (ROWS * HP)
#define LOG2E 1.442695041f
#define MFMA(a,b,c) __builtin_amdgcn_mfma_f32_16x16x32_f16((a),(b),(c),0,0,0)

// Batch-split redesign: wave w -> batch-half bh=w>>2 (chunks {2bh,2bh+1}),
// dim-group dg=w&3 (32 output dims as 2 m-tiles). Halves the 8x-replicated
// LDS h-reads (160KB->80KB per CU-step; LDS was a co-equal ~2.5k-cyc pipe
// with matrix 2.3k and VALU 2.6k). Wg doubles to 96 regs -> w1 moved to LDS,
// r/z/n biases ride the x-vector 1.0 slot (Wx[6]). Cap 256 @ (512,2).
__global__ __launch_bounds__(512, 2)
void traj_gru(const float* __restrict__ history,
              const float* __restrict__ w_ih, const float* __restrict__ w_hh,
              const float* __restrict__ b_ih, const float* __restrict__ b_hh,
              const float* __restrict__ w1, const float* __restrict__ b1,
              const float* __restrict__ w2, const float* __restrict__ b2,
              float* __restrict__ out)
{
    __shared__ __align__(16) _Float16 hbuf[2 * HBUFSZ];     // 34,816 B; a1 aliases dead half
    __shared__ __align__(16) _Float16 xhist[50 * ROWS * 6]; // 38,400 B compact [t][row][6]
    __shared__ __align__(16) _Float16 xdec[ROWS * 8];       //  1,024 B
    __shared__ __align__(16) _Float16 w2f[4 * 4 * 16 * 8];  //  4,096 B
    __shared__ __align__(16) _Float16 w1f[4 * 4 * 128 * 8]; // 32,768 B => 111,104 total

    const int tid  = threadIdx.x;
    const int wave = tid >> 6;
    const int lane = tid & 63;
    const int ln16 = lane & 15;
    const int q    = lane >> 4;
    const int bh   = wave >> 2;              // batch half: chunks {2bh, 2bh+1}
    const int dg   = wave & 3;               // dim group: dims dg*32 .. dg*32+31
    const int rowbase = blockIdx.x * ROWS;

    // ---- init LDS: zeros first, barrier, then fills ----
    for (int i = tid; i < 2 * HBUFSZ; i += 512) hbuf[i] = (_Float16)0;
    for (int i = tid; i < ROWS * 8; i += 512) xdec[i] = (_Float16)0;
    for (int i = tid; i < 4 * 4 * 16 * 8; i += 512) w2f[i] = (_Float16)0;
    __syncthreads();
    for (int idx = tid; idx < ROWS * 300; idx += 512) {
        int r = idx / 300, rem = idx - r * 300;
        int t = rem / 6, c = rem - t * 6;
        xhist[(t * ROWS + r) * 6 + c] = (_Float16)history[(rowbase + r) * 300 + rem];
    }
    if (tid < ROWS) xdec[tid * 8 + 6] = (_Float16)1.0f;   // decoder bias slot
    for (int idx = tid; idx < 6 * 128; idx += 512) {      // w2 -> B-frag layout
        int n = idx >> 7, k = idx & 127;
        int kt = k >> 5, qq = (k >> 3) & 3, j = k & 7;
        w2f[((kt * 4 + qq) * 16 + n) * 8 + j] = (_Float16)w2[n * 128 + k];
    }
    for (int idx = tid; idx < 16384; idx += 512) {        // w1 -> B-frag layout in LDS
        int j = idx & 7, d = (idx >> 3) & 127, fq = idx >> 10;
        int kt = fq >> 2, qq = fq & 3;
        w1f[idx] = (_Float16)w1[d * 128 + kt * 32 + qq * 8 + j];  // layout == idx
    }

    // ---- persistent register fragments ----
    // GRU (transposed): A-side weights, m=ln16 -> dim dg*32+mt*16+ln16,
    // k=kt*32+q*8+j. r,z scaled -log2e; n by -2log2e.
    half8 Wg[3][4][2];
    #pragma unroll
    for (int g = 0; g < 3; ++g) {
        float sc = (g < 2) ? -LOG2E : -2.0f * LOG2E;
        #pragma unroll
        for (int mt = 0; mt < 2; ++mt) {
            #pragma unroll
            for (int kt = 0; kt < 4; ++kt) {
                const float* p = w_hh + (g * 128 + dg * 32 + mt * 16 + ln16) * 128 + kt * 32 + q * 8;
                half8 v;
                #pragma unroll
                for (int j = 0; j < 8; ++j) v[j] = (_Float16)(p[j] * sc);
                Wg[g][kt][mt] = v;
            }
        }
    }
    // Wx: x-weights + (for r,z,n) bias in slot 6 (multiplies the x-vector 1.0)
    half8 Wx[3][2];
    #pragma unroll
    for (int g = 0; g < 3; ++g) {
        float sc = (g < 2) ? -LOG2E : -2.0f * LOG2E;
        #pragma unroll
        for (int mt = 0; mt < 2; ++mt) {
            half8 v;
            #pragma unroll
            for (int j = 0; j < 8; ++j) v[j] = (_Float16)0.0f;
            if (q == 0) {
                int d = dg * 32 + mt * 16 + ln16;
                #pragma unroll
                for (int j = 0; j < 6; ++j) v[j] = (_Float16)(w_ih[(g * 128 + d) * 6 + j] * sc);
                float bias;
                if      (g == 0) bias = b_ih[d]       + b_hh[d];
                else if (g == 1) bias = b_ih[128 + d] + b_hh[128 + d];
                else             bias = b_ih[256 + d];
                v[6] = (_Float16)(bias * sc);
            }
            Wx[g][mt] = v;
        }
    }
    // hh-acc init: b_hh n-part (C-layout: row = dim dg*32+mt*16+q*4+i)
    f32x4 bhn[2];
    #pragma unroll
    for (int mt = 0; mt < 2; ++mt)
        #pragma unroll
        for (int i = 0; i < 4; ++i)
            bhn[mt][i] = b_hh[256 + dg * 32 + mt * 16 + q * 4 + i] * (-2.0f * LOG2E);

    float b1rv[2];
    b1rv[0] = b1[dg * 32 + ln16];
    b1rv[1] = b1[dg * 32 + 16 + ln16];
    const float b2r = (ln16 < 6) ? b2[ln16] : 0.0f;

    float hp[2][2][4] = {};  // [c2][mt][i]: (batch=(2bh+c2)*16+ln16, dim=dg*32+mt*16+q*4+i)

    __syncthreads();

    // ---- GRU step: 2 chunks x 2 m-tiles per wave ----
    auto gru_step = [&](int p, int t, bool enc) {
        const _Float16* hb = hbuf + p * HBUFSZ;
        _Float16*       hn = hbuf + (p ^ 1) * HBUFSZ;
        half8 Bf[2][4], Bx[2];

        auto loadB = [&](int c2) {
            int c = 2 * bh + c2;
            const _Float16* rp = hb + (c * 16 + ln16) * HP;
            #pragma unroll
            for (int kt = 0; kt < 4; ++kt)
                Bf[c2][kt] = *(const half8*)(rp + kt * 32 + q * 8);
            if (enc) {   // compact [t][row][6] + [1.0, 0] packed in regs
                const int* xi = (const int*)xhist;
                int base = (t * ROWS + c * 16 + ln16) * 3;
                int4v dv = { xi[base], xi[base + 1], xi[base + 2], 0x3C00 };
                Bx[c2] = __builtin_bit_cast(half8, dv);
            } else {
                Bx[c2] = *(const half8*)(xdec + (c * 16 + ln16) * 8);
            }
        };
        auto mfmas = [&](int c2, f32x4 (&A)[2][4]) {
            #pragma unroll
            for (int mt = 0; mt < 2; ++mt) {
                f32x4 r = {0,0,0,0}, z = {0,0,0,0}, n = {0,0,0,0}, hh = bhn[mt];
                #pragma unroll
                for (int kt = 0; kt < 4; ++kt) {
                    r  = MFMA(Wg[0][kt][mt], Bf[c2][kt], r);
                    z  = MFMA(Wg[1][kt][mt], Bf[c2][kt], z);
                    hh = MFMA(Wg[2][kt][mt], Bf[c2][kt], hh);
                }
                r = MFMA(Wx[0][mt], Bx[c2], r);   // slot6 carries (b_ih+b_hh) r-bias
                z = MFMA(Wx[1][mt], Bx[c2], z);
                n = MFMA(Wx[2][mt], Bx[c2], n);   // slot6 carries b_ih n-bias
                A[mt][0] = r; A[mt][1] = z; A[mt][2] = hh; A[mt][3] = n;
            }
        };
        auto gates = [&](int c2, f32x4 (&A)[2][4]) {
            int c = 2 * bh + c2;
            #pragma unroll
            for (int mt = 0; mt < 2; ++mt) {
                half4 hv;
                #pragma unroll
                for (int i = 0; i < 4; ++i) {
                    float rr = __builtin_amdgcn_rcpf(1.0f + __builtin_amdgcn_exp2f(A[mt][0][i]));
                    float zz = __builtin_amdgcn_rcpf(1.0f + __builtin_amdgcn_exp2f(A[mt][1][i]));
                    float tt = A[mt][3][i] + rr * A[mt][2][i];
                    float nn = 2.0f * __builtin_amdgcn_rcpf(1.0f + __builtin_amdgcn_exp2f(tt)) - 1.0f;
                    float h = nn + zz * (hp[c2][mt][i] - nn);
                    hp[c2][mt][i] = h;
                    hv[i] = (_Float16)h;
                }
                *(half4*)(hn + (c * 16 + ln16) * HP + dg * 32 + mt * 16 + q * 4) = hv;
            }
        };

        f32x4 accA[2][4], accB[2][4];
        loadB(0);
        mfmas(0, accA);
        loadB(1);            // issue chunk-1 LDS reads under chunk-0 gates
        gates(0, accA);
        mfmas(1, accB);
        gates(1, accB);
        __syncthreads();
    };

    // ---- head step: phase1 batch-split (w1 frags from LDS); phase2 as r0 ----
    auto head_step = [&](int f, int p) {
        const _Float16* hb = hbuf + p * HBUFSZ;
        _Float16*       a1s = hbuf + (p ^ 1) * HBUFSZ;   // dead ping-pong half
        half8 Bw[4][2];
        #pragma unroll
        for (int kt = 0; kt < 4; ++kt)
            #pragma unroll
            for (int nt = 0; nt < 2; ++nt)
                Bw[kt][nt] = *(const half8*)(w1f + ((kt * 4 + q) * 128 + dg * 32 + nt * 16 + ln16) * 8);
        #pragma unroll
        for (int c2 = 0; c2 < 2; ++c2) {
            int c = 2 * bh + c2;
            const _Float16* rp = hb + (c * 16 + ln16) * HP;
            half8 Ah[4];
            #pragma unroll
            for (int kt = 0; kt < 4; ++kt)
                Ah[kt] = *(const half8*)(rp + kt * 32 + q * 8);
            f32x4 a0 = {0,0,0,0}, a1v = {0,0,0,0};
            #pragma unroll
            for (int kt = 0; kt < 4; ++kt) {
                a0  = MFMA(Ah[kt], Bw[kt][0], a0);
                a1v = MFMA(Ah[kt], Bw[kt][1], a1v);
            }
            // stored col[6:5] = dim[6:5] ^ batchrow[1:0] (=i); dim[6:5]=dg, dim[4]=nt
            #pragma unroll
            for (int i = 0; i < 4; ++i) {
                float v0 = a0[i] + b1rv[0];
                v0 = v0 > 0.0f ? v0 : 0.0f;
                a1s[(c * 16 + q * 4 + i) * HP + ((dg ^ i) << 5) + ln16] = (_Float16)v0;
                float v1 = a1v[i] + b1rv[1];
                v1 = v1 > 0.0f ? v1 : 0.0f;
                a1s[(c * 16 + q * 4 + i) * HP + ((dg ^ i) << 5) + 16 + ln16] = (_Float16)v1;
            }
        }
        __syncthreads();
        if (wave < 4) {   // phase 2: A=a1 (m=batch), B=w2f (n=out-dim) — unchanged
            const int sw = ln16 & 3;
            const _Float16* rp = a1s + (wave * 16 + ln16) * HP;
            f32x4 o = {0,0,0,0};
            #pragma unroll
            for (int kt = 0; kt < 4; ++kt) {
                half8 Aa = *(const half8*)(rp + ((kt ^ sw) << 5) + q * 8);
                half8 Bw2 = *(const half8*)&w2f[((kt * 4 + q) * 16 + ln16) * 8];
                o = MFMA(Aa, Bw2, o);
            }
            if (ln16 < 6) {
                #pragma unroll
                for (int i = 0; i < 4; ++i) {
                    int row = wave * 16 + q * 4 + i;
                    float v = o[i] + b2r;
                    out[(rowbase + row) * 180 + f * 6 + ln16] = v;
                    xdec[row * 8 + ln16] = (_Float16)v;   // next decoder x
                }
            }
        }
        __syncthreads();
    };

    int p = 0;
    #pragma unroll 1
    for (int t = 0; t < 50; ++t) { gru_step(p, t, true); p ^= 1; }
    #pragma unroll 1
    for (int f = 0; f < 30; ++f) {
        gru_step(p, f == 0 ? 49 : 0, f == 0);   // f=0: x = history[:,49]
        p ^= 1;
        head_step(f, p);
    }
}

extern "C" void kernel_launch(void* const* d_in, const int* in_sizes, int n_in,
                              void* d_out, int out_size, void* d_ws, size_t ws_size,
                              hipStream_t stream) {
    (void)in_sizes; (void)n_in; (void)d_ws; (void)ws_size; (void)out_size;
    traj_gru<<<dim3(16384 / ROWS), dim3(512), 0, stream>>>(
        (const float*)d_in[0], (const float*)d_in[1], (const float*)d_in[2],
        (const float*)d_in[3], (const float*)d_in[4], (const float*)d_in[5],
        (const float*)d_in[6], (const float*)d_in[7], (const float*)d_in[8],
        (float*)d_out);
}